// Round 2
// baseline (9504.354 us; speedup 1.0000x reference)
//
#include <hip/hip_runtime.h>
#include <hip/hip_bf16.h>

// ---------------------------------------------------------------------------
// C[M,N] = A[M,K] @ W[N,K]^T + bias[N]   (f32, 64x64 tile, 4x4 microtile)
// ---------------------------------------------------------------------------
__global__ __launch_bounds__(256, 2)
void gemm_bt(const float* __restrict__ A, const float* __restrict__ W,
             const float* __restrict__ bias, float* __restrict__ C,
             int M, int N, int K) {
  __shared__ float As[16][68];
  __shared__ float Ws[16][68];
  const int t  = threadIdx.x;
  const int tx = t & 15, ty = t >> 4;
  const int m0 = blockIdx.y * 64, n0 = blockIdx.x * 64;
  const int lr = t >> 2;
  const int lk = (t & 3) * 4;

  float acc[4][4];
  #pragma unroll
  for (int i = 0; i < 4; ++i)
    #pragma unroll
    for (int j = 0; j < 4; ++j) acc[i][j] = 0.f;

  for (int k0 = 0; k0 < K; k0 += 16) {
    int am = m0 + lr; if (am > M - 1) am = M - 1;
    const float4 a4 = *(const float4*)&A[(size_t)am * K + k0 + lk];
    const float4 w4 = *(const float4*)&W[(size_t)(n0 + lr) * K + k0 + lk];
    __syncthreads();
    As[lk + 0][lr] = a4.x; As[lk + 1][lr] = a4.y;
    As[lk + 2][lr] = a4.z; As[lk + 3][lr] = a4.w;
    Ws[lk + 0][lr] = w4.x; Ws[lk + 1][lr] = w4.y;
    Ws[lk + 2][lr] = w4.z; Ws[lk + 3][lr] = w4.w;
    __syncthreads();
    #pragma unroll
    for (int kk = 0; kk < 16; ++kk) {
      const float4 av = *(const float4*)&As[kk][ty * 4];
      const float4 wv = *(const float4*)&Ws[kk][tx * 4];
      const float ar[4] = {av.x, av.y, av.z, av.w};
      const float wr[4] = {wv.x, wv.y, wv.z, wv.w};
      #pragma unroll
      for (int i = 0; i < 4; ++i)
        #pragma unroll
        for (int j = 0; j < 4; ++j) acc[i][j] = fmaf(ar[i], wr[j], acc[i][j]);
    }
  }
  #pragma unroll
  for (int i = 0; i < 4; ++i) {
    const int m = m0 + ty * 4 + i;
    if (m < M) {
      #pragma unroll
      for (int j = 0; j < 4; ++j) {
        const int n = n0 + tx * 4 + j;
        C[(size_t)m * N + n] = acc[i][j] + bias[n];
      }
    }
  }
}

// ---------------------------------------------------------------------------
// Fused cpb-MLP + flash attention.
// Block = (b, 8 q-rows), 256 threads, chunks of 32 keys.
//   MLP/QK role: thread = (qi = t>>5, kk = t&31) owns one (q,k) pair.
//                MLP weights live in LDS (wave-uniform broadcast reads) --
//                NO per-thread weight registers (round-1 spill fix).
//   PV role:     thread = output dim e = t (head he = t>>5).
//   p staged as ps[h][qi][kk]: consecutive-kk writes (conflict-free),
//   aligned float4 broadcast reads in PV.
// ---------------------------------------------------------------------------
#define QT 8
#define KC 32

__global__ __launch_bounds__(256, 2)
void attn_cpb(const float* __restrict__ qbuf,   // [B,900,256]
              const float* __restrict__ kvbuf,  // [B,1024,512] (k | v)
              const float* __restrict__ dist,   // [B,900,1024,2]
              const unsigned char* __restrict__ mask, // [B,1024]
              const float* __restrict__ Wc1, const float* __restrict__ bc1,
              const float* __restrict__ Wc2, const float* __restrict__ bc2,
              float* __restrict__ obuf) {       // [B,900,256]
  __shared__ float qs[QT][256];        // 8 KB
  __shared__ float ks[KC][256];        // 32 KB, xor-swizzled columns
  __shared__ float ps[8][QT][KC];      // 8 KB  p[h][qi][kk]
  __shared__ float4 wc1s[64];          // 1 KB  (w1x, w1y, b1, 0)
  __shared__ float4 wc2s[64][2];       // 2 KB  Wc2 transposed [j][h]
  __shared__ float mstate[QT][8], lstate[QT][8], astate[QT][8];

  const int t  = threadIdx.x;
  const int b  = blockIdx.x / 113;
  const int q0 = (blockIdx.x % 113) * QT;

  // --- stage MLP weights into LDS (once) ---
  if (t < 64) {
    wc1s[t] = make_float4(Wc1[t * 2], Wc1[t * 2 + 1], bc1[t], 0.f);
    wc2s[t][0] = make_float4(Wc2[0 * 64 + t], Wc2[1 * 64 + t],
                             Wc2[2 * 64 + t], Wc2[3 * 64 + t]);
    wc2s[t][1] = make_float4(Wc2[4 * 64 + t], Wc2[5 * 64 + t],
                             Wc2[6 * 64 + t], Wc2[7 * 64 + t]);
  }
  float b2r[8];
  #pragma unroll
  for (int h = 0; h < 8; ++h) b2r[h] = bc2[h];   // uniform -> SGPRs

  // --- stage q rows (clamped; tail rows duplicated, stores guarded) ---
  #pragma unroll
  for (int j = 0; j < 2; ++j) {
    const int f = t + 256 * j;
    const int row = f >> 6, c = (f & 63) * 4;
    int q = q0 + row; if (q > 899) q = 899;
    *(float4*)&qs[row][c] =
        *(const float4*)&qbuf[((size_t)(b * 900 + q)) * 256 + c];
  }
  if (t < 64) {
    mstate[t >> 3][t & 7] = -1e30f;
    lstate[t >> 3][t & 7] = 0.f;
  }
  float O[QT];
  #pragma unroll
  for (int i = 0; i < QT; ++i) O[i] = 0.f;

  const int qi  = t >> 5, kk = t & 31;
  const int swz = (kk & 7) << 2;
  int qc = q0 + qi; if (qc > 899) qc = 899;
  const size_t dist_row = (((size_t)(b * 900 + qc)) * 1024) * 2;
  const int he = t >> 5;
  __syncthreads();

  for (int c = 0; c < 1024 / KC; ++c) {
    const int k0 = c * KC;
    // ---- stage K chunk into LDS (xor-swizzle columns by row) ----
    #pragma unroll
    for (int j = 0; j < 8; ++j) {
      const int f = t + 256 * j;
      const int row = f >> 6, col = (f & 63) * 4;
      const int sc = col ^ ((row & 7) << 2);
      *(float4*)&ks[row][sc] =
          *(const float4*)&kvbuf[((size_t)(b * 1024 + k0 + row)) * 512 + col];
    }
    __syncthreads();

    // ---- cpb MLP: each thread computes its own pair, weights from LDS ----
    const float2 d2 = *(const float2*)&dist[dist_row + (size_t)(k0 + kk) * 2];
    float cp[8];
    #pragma unroll
    for (int h = 0; h < 8; ++h) cp[h] = b2r[h];
    #pragma unroll
    for (int jl = 0; jl < 64; ++jl) {
      const float4 w1 = wc1s[jl];
      const float hv =
          fmaxf(fmaf(w1.x, d2.x, fmaf(w1.y, d2.y, w1.z)), 0.f);
      const float4 wa = wc2s[jl][0];
      const float4 wb = wc2s[jl][1];
      cp[0] = fmaf(wa.x, hv, cp[0]); cp[1] = fmaf(wa.y, hv, cp[1]);
      cp[2] = fmaf(wa.z, hv, cp[2]); cp[3] = fmaf(wa.w, hv, cp[3]);
      cp[4] = fmaf(wb.x, hv, cp[4]); cp[5] = fmaf(wb.y, hv, cp[5]);
      cp[6] = fmaf(wb.z, hv, cp[6]); cp[7] = fmaf(wb.w, hv, cp[7]);
    }

    // ---- QK dot products ----
    float acc[8];
    #pragma unroll
    for (int h = 0; h < 8; ++h) acc[h] = 0.f;
    #pragma unroll
    for (int d4 = 0; d4 < 8; ++d4) {
      #pragma unroll
      for (int h = 0; h < 8; ++h) {
        const int d = h * 32 + d4 * 4;
        const float4 q4 = *(const float4*)&qs[qi][d];
        const float4 k4 = *(const float4*)&ks[kk][d ^ swz];
        acc[h] = fmaf(q4.x, k4.x, acc[h]);
        acc[h] = fmaf(q4.y, k4.y, acc[h]);
        acc[h] = fmaf(q4.z, k4.z, acc[h]);
        acc[h] = fmaf(q4.w, k4.w, acc[h]);
      }
    }

    // ---- scores + online softmax (32-lane group per (qi,h)) ----
    const bool msk = mask[b * 1024 + k0 + kk] != 0;
    #pragma unroll
    for (int h = 0; h < 8; ++h) {
      const float sh =
          msk ? -1e30f : fmaf(acc[h], 0.17677669529663687f, cp[h]);
      float cmax = sh;
      cmax = fmaxf(cmax, __shfl_xor(cmax, 1));
      cmax = fmaxf(cmax, __shfl_xor(cmax, 2));
      cmax = fmaxf(cmax, __shfl_xor(cmax, 4));
      cmax = fmaxf(cmax, __shfl_xor(cmax, 8));
      cmax = fmaxf(cmax, __shfl_xor(cmax, 16));
      const float mold = mstate[qi][h];
      const float mnew = fmaxf(mold, cmax);
      const float al   = __expf(mold - mnew);
      const float p    = __expf(sh - mnew);
      ps[h][qi][kk] = p;
      float psum = p;
      psum += __shfl_xor(psum, 1);
      psum += __shfl_xor(psum, 2);
      psum += __shfl_xor(psum, 4);
      psum += __shfl_xor(psum, 8);
      psum += __shfl_xor(psum, 16);
      if (kk == 0) {
        mstate[qi][h] = mnew;
        lstate[qi][h] = lstate[qi][h] * al + psum;
        astate[qi][h] = al;
      }
    }
    __syncthreads();

    // ---- PV: thread owns output dim e = t; key-group outer (low regs) ----
    #pragma unroll
    for (int i = 0; i < QT; ++i) O[i] *= astate[i][he];
    const float* vp = kvbuf + ((size_t)(b * 1024 + k0)) * 512 + 256 + t;
    #pragma unroll
    for (int g = 0; g < KC / 4; ++g) {
      const float v0 = vp[(size_t)(g * 4 + 0) * 512];
      const float v1 = vp[(size_t)(g * 4 + 1) * 512];
      const float v2 = vp[(size_t)(g * 4 + 2) * 512];
      const float v3 = vp[(size_t)(g * 4 + 3) * 512];
      #pragma unroll
      for (int i = 0; i < QT; ++i) {
        const float4 p4 = *(const float4*)&ps[he][i][g * 4];
        float o = O[i];
        o = fmaf(p4.x, v0, o); o = fmaf(p4.y, v1, o);
        o = fmaf(p4.z, v2, o); o = fmaf(p4.w, v3, o);
        O[i] = o;
      }
    }
    __syncthreads();
  }

  #pragma unroll
  for (int i = 0; i < QT; ++i) {
    const int q = q0 + i;
    if (q < 900)
      obuf[((size_t)(b * 900 + q)) * 256 + t] = O[i] / lstate[i][he];
  }
}

// ---------------------------------------------------------------------------
extern "C" void kernel_launch(void* const* d_in, const int* in_sizes, int n_in,
                              void* d_out, int out_size, void* d_ws, size_t ws_size,
                              hipStream_t stream) {
  const float* nodes  = (const float*)d_in[0];
  const float* images = (const float*)d_in[1];
  const unsigned char* mask = (const unsigned char*)d_in[2];
  const float* dist   = (const float*)d_in[3];
  const float* Wq     = (const float*)d_in[4];
  const float* bq     = (const float*)d_in[5];
  const float* Wkv    = (const float*)d_in[6];
  const float* bkv    = (const float*)d_in[7];
  const float* Wc1    = (const float*)d_in[8];
  const float* bc1    = (const float*)d_in[9];
  const float* Wc2    = (const float*)d_in[10];
  const float* bc2    = (const float*)d_in[11];
  const float* Wo     = (const float*)d_in[12];
  const float* bo     = (const float*)d_in[13];
  float* out = (float*)d_out;

  float* qbuf  = (float*)d_ws;                 // 3600*256
  float* kvbuf = qbuf + 3600 * 256;            // 4096*512
  float* obuf  = kvbuf + 4096 * 512;           // 3600*256

  gemm_bt<<<dim3(4, 57), 256, 0, stream>>>(nodes,  Wq,  bq,  qbuf,  3600, 256, 256);
  gemm_bt<<<dim3(8, 64), 256, 0, stream>>>(images, Wkv, bkv, kvbuf, 4096, 512, 256);
  attn_cpb<<<dim3(452), 256, 0, stream>>>(qbuf, kvbuf, dist, mask,
                                          Wc1, bc1, Wc2, bc2, obuf);
  gemm_bt<<<dim3(4, 57), 256, 0, stream>>>(obuf, Wo, bo, out, 3600, 256, 256);
}

// Round 3
// 1371.807 us; speedup vs baseline: 6.9283x; 6.9283x over previous
//
#include <hip/hip_runtime.h>
#include <hip/hip_bf16.h>

// ---------------------------------------------------------------------------
// C[M,N] = A[M,K] @ W[N,K]^T + bias[N]   (f32, 64x64 tile, 4x4 microtile)
// ---------------------------------------------------------------------------
__global__ __launch_bounds__(256, 2)
void gemm_bt(const float* __restrict__ A, const float* __restrict__ W,
             const float* __restrict__ bias, float* __restrict__ C,
             int M, int N, int K) {
  __shared__ float As[16][68];
  __shared__ float Ws[16][68];
  const int t  = threadIdx.x;
  const int tx = t & 15, ty = t >> 4;
  const int m0 = blockIdx.y * 64, n0 = blockIdx.x * 64;
  const int lr = t >> 2;
  const int lk = (t & 3) * 4;

  float acc[4][4];
  #pragma unroll
  for (int i = 0; i < 4; ++i)
    #pragma unroll
    for (int j = 0; j < 4; ++j) acc[i][j] = 0.f;

  for (int k0 = 0; k0 < K; k0 += 16) {
    int am = m0 + lr; if (am > M - 1) am = M - 1;
    const float4 a4 = *(const float4*)&A[(size_t)am * K + k0 + lk];
    const float4 w4 = *(const float4*)&W[(size_t)(n0 + lr) * K + k0 + lk];
    __syncthreads();
    As[lk + 0][lr] = a4.x; As[lk + 1][lr] = a4.y;
    As[lk + 2][lr] = a4.z; As[lk + 3][lr] = a4.w;
    Ws[lk + 0][lr] = w4.x; Ws[lk + 1][lr] = w4.y;
    Ws[lk + 2][lr] = w4.z; Ws[lk + 3][lr] = w4.w;
    __syncthreads();
    #pragma unroll
    for (int kk = 0; kk < 16; ++kk) {
      const float4 av = *(const float4*)&As[kk][ty * 4];
      const float4 wv = *(const float4*)&Ws[kk][tx * 4];
      const float ar[4] = {av.x, av.y, av.z, av.w};
      const float wr[4] = {wv.x, wv.y, wv.z, wv.w};
      #pragma unroll
      for (int i = 0; i < 4; ++i)
        #pragma unroll
        for (int j = 0; j < 4; ++j) acc[i][j] = fmaf(ar[i], wr[j], acc[i][j]);
    }
  }
  #pragma unroll
  for (int i = 0; i < 4; ++i) {
    const int m = m0 + ty * 4 + i;
    if (m < M) {
      #pragma unroll
      for (int j = 0; j < 4; ++j) {
        const int n = n0 + tx * 4 + j;
        C[(size_t)m * N + n] = acc[i][j] + bias[n];
      }
    }
  }
}

// ---------------------------------------------------------------------------
// Fused cpb-MLP + flash attention.
// Block = (b, 8 q-rows), 256 threads, chunks of 32 keys.
// MLP weights in LDS, consumed in blocks of 4 hidden units with a
// sched_barrier(0) fence per block: caps the load live-range at ~48 VGPRs
// so the round-1/2 catastrophic spill (compiler hoisting 192 float4 loads)
// cannot recur.
// ---------------------------------------------------------------------------
#define QT 8
#define KC 32

__global__ __launch_bounds__(256, 2)
void attn_cpb(const float* __restrict__ qbuf,   // [B,900,256]
              const float* __restrict__ kvbuf,  // [B,1024,512] (k | v)
              const float* __restrict__ dist,   // [B,900,1024,2]
              const unsigned char* __restrict__ mask, // [B,1024]
              const float* __restrict__ Wc1, const float* __restrict__ bc1,
              const float* __restrict__ Wc2, const float* __restrict__ bc2,
              float* __restrict__ obuf) {       // [B,900,256]
  __shared__ float qs[QT][256];        // 8 KB
  __shared__ float ks[KC][256];        // 32 KB, xor-swizzled columns
  __shared__ float ps[8][QT][KC];      // 8 KB  p[h][qi][kk]
  __shared__ float4 wpack[64][3];      // 3 KB  {w1x,w1y,b1,_},{Wc2[0..3]},{Wc2[4..7]}
  __shared__ float mstate[QT][8], lstate[QT][8], astate[QT][8];

  const int t  = threadIdx.x;
  const int b  = blockIdx.x / 113;
  const int q0 = (blockIdx.x % 113) * QT;

  // --- stage MLP weights into LDS (once) ---
  if (t < 64) {
    wpack[t][0] = make_float4(Wc1[t * 2], Wc1[t * 2 + 1], bc1[t], 0.f);
    wpack[t][1] = make_float4(Wc2[0 * 64 + t], Wc2[1 * 64 + t],
                              Wc2[2 * 64 + t], Wc2[3 * 64 + t]);
    wpack[t][2] = make_float4(Wc2[4 * 64 + t], Wc2[5 * 64 + t],
                              Wc2[6 * 64 + t], Wc2[7 * 64 + t]);
  }
  float b2r[8];
  #pragma unroll
  for (int h = 0; h < 8; ++h) b2r[h] = bc2[h];   // uniform -> SGPRs

  // --- stage q rows (clamped; tail rows duplicated, stores guarded) ---
  #pragma unroll
  for (int j = 0; j < 2; ++j) {
    const int f = t + 256 * j;
    const int row = f >> 6, c = (f & 63) * 4;
    int q = q0 + row; if (q > 899) q = 899;
    *(float4*)&qs[row][c] =
        *(const float4*)&qbuf[((size_t)(b * 900 + q)) * 256 + c];
  }
  if (t < 64) {
    mstate[t >> 3][t & 7] = -1e30f;
    lstate[t >> 3][t & 7] = 0.f;
  }
  float O[QT];
  #pragma unroll
  for (int i = 0; i < QT; ++i) O[i] = 0.f;

  const int qi  = t >> 5, kk = t & 31;
  const int swz = (kk & 7) << 2;
  int qc = q0 + qi; if (qc > 899) qc = 899;
  const size_t dist_row = (((size_t)(b * 900 + qc)) * 1024) * 2;
  const int he = t >> 5;
  __syncthreads();

  for (int c = 0; c < 1024 / KC; ++c) {
    const int k0 = c * KC;
    // ---- stage K chunk into LDS (xor-swizzle columns by row) ----
    #pragma unroll
    for (int j = 0; j < 8; ++j) {
      const int f = t + 256 * j;
      const int row = f >> 6, col = (f & 63) * 4;
      const int sc = col ^ ((row & 7) << 2);
      *(float4*)&ks[row][sc] =
          *(const float4*)&kvbuf[((size_t)(b * 1024 + k0 + row)) * 512 + col];
    }
    __syncthreads();

    // ---- cpb MLP: own pair, weights via LDS broadcast, fenced blocks ----
    const float2 d2 = *(const float2*)&dist[dist_row + (size_t)(k0 + kk) * 2];
    float cp[8];
    #pragma unroll
    for (int h = 0; h < 8; ++h) cp[h] = b2r[h];
    for (int jo = 0; jo < 16; ++jo) {        // 16 x 4 hidden units
      #pragma unroll
      for (int ji = 0; ji < 4; ++ji) {
        const int jl = jo * 4 + ji;
        const float4 w1 = wpack[jl][0];
        const float hv =
            fmaxf(fmaf(w1.x, d2.x, fmaf(w1.y, d2.y, w1.z)), 0.f);
        const float4 wa = wpack[jl][1];
        const float4 wb = wpack[jl][2];
        cp[0] = fmaf(wa.x, hv, cp[0]); cp[1] = fmaf(wa.y, hv, cp[1]);
        cp[2] = fmaf(wa.z, hv, cp[2]); cp[3] = fmaf(wa.w, hv, cp[3]);
        cp[4] = fmaf(wb.x, hv, cp[4]); cp[5] = fmaf(wb.y, hv, cp[5]);
        cp[6] = fmaf(wb.z, hv, cp[6]); cp[7] = fmaf(wb.w, hv, cp[7]);
      }
      __builtin_amdgcn_sched_barrier(0);     // cap load live-range (no hoist)
    }

    // ---- QK dot products ----
    float acc[8];
    #pragma unroll
    for (int h = 0; h < 8; ++h) acc[h] = 0.f;
    #pragma unroll
    for (int d4 = 0; d4 < 8; ++d4) {
      #pragma unroll
      for (int h = 0; h < 8; ++h) {
        const int d = h * 32 + d4 * 4;
        const float4 q4 = *(const float4*)&qs[qi][d];
        const float4 k4 = *(const float4*)&ks[kk][d ^ swz];
        acc[h] = fmaf(q4.x, k4.x, acc[h]);
        acc[h] = fmaf(q4.y, k4.y, acc[h]);
        acc[h] = fmaf(q4.z, k4.z, acc[h]);
        acc[h] = fmaf(q4.w, k4.w, acc[h]);
      }
    }

    // ---- scores + online softmax (32-lane group per (qi,h)) ----
    const bool msk = mask[b * 1024 + k0 + kk] != 0;
    #pragma unroll
    for (int h = 0; h < 8; ++h) {
      const float sh =
          msk ? -1e30f : fmaf(acc[h], 0.17677669529663687f, cp[h]);
      float cmax = sh;
      cmax = fmaxf(cmax, __shfl_xor(cmax, 1));
      cmax = fmaxf(cmax, __shfl_xor(cmax, 2));
      cmax = fmaxf(cmax, __shfl_xor(cmax, 4));
      cmax = fmaxf(cmax, __shfl_xor(cmax, 8));
      cmax = fmaxf(cmax, __shfl_xor(cmax, 16));
      const float mold = mstate[qi][h];
      const float mnew = fmaxf(mold, cmax);
      const float al   = __expf(mold - mnew);
      const float p    = __expf(sh - mnew);
      ps[h][qi][kk] = p;
      float psum = p;
      psum += __shfl_xor(psum, 1);
      psum += __shfl_xor(psum, 2);
      psum += __shfl_xor(psum, 4);
      psum += __shfl_xor(psum, 8);
      psum += __shfl_xor(psum, 16);
      if (kk == 0) {
        mstate[qi][h] = mnew;
        lstate[qi][h] = lstate[qi][h] * al + psum;
        astate[qi][h] = al;
      }
    }
    __syncthreads();

    // ---- PV: thread owns output dim e = t; key-group outer ----
    #pragma unroll
    for (int i = 0; i < QT; ++i) O[i] *= astate[i][he];
    const float* vp = kvbuf + ((size_t)(b * 1024 + k0)) * 512 + 256 + t;
    #pragma unroll
    for (int g = 0; g < KC / 4; ++g) {
      const float v0 = vp[(size_t)(g * 4 + 0) * 512];
      const float v1 = vp[(size_t)(g * 4 + 1) * 512];
      const float v2 = vp[(size_t)(g * 4 + 2) * 512];
      const float v3 = vp[(size_t)(g * 4 + 3) * 512];
      #pragma unroll
      for (int i = 0; i < QT; ++i) {
        const float4 p4 = *(const float4*)&ps[he][i][g * 4];
        float o = O[i];
        o = fmaf(p4.x, v0, o); o = fmaf(p4.y, v1, o);
        o = fmaf(p4.z, v2, o); o = fmaf(p4.w, v3, o);
        O[i] = o;
      }
    }
    __syncthreads();
  }

  #pragma unroll
  for (int i = 0; i < QT; ++i) {
    const int q = q0 + i;
    if (q < 900)
      obuf[((size_t)(b * 900 + q)) * 256 + t] = O[i] / lstate[i][he];
  }
}

// ---------------------------------------------------------------------------
extern "C" void kernel_launch(void* const* d_in, const int* in_sizes, int n_in,
                              void* d_out, int out_size, void* d_ws, size_t ws_size,
                              hipStream_t stream) {
  const float* nodes  = (const float*)d_in[0];
  const float* images = (const float*)d_in[1];
  const unsigned char* mask = (const unsigned char*)d_in[2];
  const float* dist   = (const float*)d_in[3];
  const float* Wq     = (const float*)d_in[4];
  const float* bq     = (const float*)d_in[5];
  const float* Wkv    = (const float*)d_in[6];
  const float* bkv    = (const float*)d_in[7];
  const float* Wc1    = (const float*)d_in[8];
  const float* bc1    = (const float*)d_in[9];
  const float* Wc2    = (const float*)d_in[10];
  const float* bc2    = (const float*)d_in[11];
  const float* Wo     = (const float*)d_in[12];
  const float* bo     = (const float*)d_in[13];
  float* out = (float*)d_out;

  float* qbuf  = (float*)d_ws;                 // 3600*256
  float* kvbuf = qbuf + 3600 * 256;            // 4096*512
  float* obuf  = kvbuf + 4096 * 512;           // 3600*256

  gemm_bt<<<dim3(4, 57), 256, 0, stream>>>(nodes,  Wq,  bq,  qbuf,  3600, 256, 256);
  gemm_bt<<<dim3(8, 64), 256, 0, stream>>>(images, Wkv, bkv, kvbuf, 4096, 512, 256);
  attn_cpb<<<dim3(452), 256, 0, stream>>>(qbuf, kvbuf, dist, mask,
                                          Wc1, bc1, Wc2, bc2, obuf);
  gemm_bt<<<dim3(4, 57), 256, 0, stream>>>(obuf, Wo, bo, out, 3600, 256, 256);
}

// Round 4
// 395.761 us; speedup vs baseline: 24.0154x; 3.4662x over previous
//
#include <hip/hip_runtime.h>
#include <hip/hip_bf16.h>

typedef float f32x4 __attribute__((ext_vector_type(4)));
typedef short short8 __attribute__((ext_vector_type(8)));

// ---------------------------------------------------------------------------
// GEMM C[M,N] = A[M,K] @ W[N,K]^T + bias[N], 64x64 tile, 4x4 microtile.
// Three epilogue variants: f32 out, bf16 out, kv-split (K->bf16, V->f32).
// ---------------------------------------------------------------------------
#define GEMM_BODY                                                            \
  __shared__ float As[16][68];                                               \
  __shared__ float Ws[16][68];                                               \
  const int t  = threadIdx.x;                                                \
  const int tx = t & 15, ty = t >> 4;                                        \
  const int m0 = blockIdx.y * 64, n0 = blockIdx.x * 64;                      \
  const int lr = t >> 2;                                                     \
  const int lk = (t & 3) * 4;                                                \
  float acc[4][4];                                                           \
  _Pragma("unroll") for (int i = 0; i < 4; ++i)                              \
      _Pragma("unroll") for (int j = 0; j < 4; ++j) acc[i][j] = 0.f;         \
  for (int k0 = 0; k0 < K; k0 += 16) {                                       \
    int am = m0 + lr; if (am > M - 1) am = M - 1;                            \
    const float4 a4 = *(const float4*)&A[(size_t)am * K + k0 + lk];          \
    const float4 w4 = *(const float4*)&W[(size_t)(n0 + lr) * K + k0 + lk];   \
    __syncthreads();                                                         \
    As[lk + 0][lr] = a4.x; As[lk + 1][lr] = a4.y;                            \
    As[lk + 2][lr] = a4.z; As[lk + 3][lr] = a4.w;                            \
    Ws[lk + 0][lr] = w4.x; Ws[lk + 1][lr] = w4.y;                            \
    Ws[lk + 2][lr] = w4.z; Ws[lk + 3][lr] = w4.w;                            \
    __syncthreads();                                                         \
    _Pragma("unroll") for (int kk = 0; kk < 16; ++kk) {                      \
      const float4 av = *(const float4*)&As[kk][ty * 4];                     \
      const float4 wv = *(const float4*)&Ws[kk][tx * 4];                     \
      const float ar[4] = {av.x, av.y, av.z, av.w};                          \
      const float wr[4] = {wv.x, wv.y, wv.z, wv.w};                          \
      _Pragma("unroll") for (int i = 0; i < 4; ++i)                          \
          _Pragma("unroll") for (int j = 0; j < 4; ++j)                      \
              acc[i][j] = fmaf(ar[i], wr[j], acc[i][j]);                     \
    }                                                                        \
  }

__global__ __launch_bounds__(256, 2)
void gemm_bt_f32(const float* __restrict__ A, const float* __restrict__ W,
                 const float* __restrict__ bias, float* __restrict__ C,
                 int M, int N, int K) {
  GEMM_BODY
  #pragma unroll
  for (int i = 0; i < 4; ++i) {
    const int m = m0 + ty * 4 + i;
    if (m < M) {
      #pragma unroll
      for (int j = 0; j < 4; ++j) {
        const int n = n0 + tx * 4 + j;
        C[(size_t)m * N + n] = acc[i][j] + bias[n];
      }
    }
  }
}

__global__ __launch_bounds__(256, 2)
void gemm_bt_bf16(const float* __restrict__ A, const float* __restrict__ W,
                  const float* __restrict__ bias, __hip_bfloat16* __restrict__ C,
                  int M, int N, int K) {
  GEMM_BODY
  #pragma unroll
  for (int i = 0; i < 4; ++i) {
    const int m = m0 + ty * 4 + i;
    if (m < M) {
      #pragma unroll
      for (int j = 0; j < 4; ++j) {
        const int n = n0 + tx * 4 + j;
        C[(size_t)m * N + n] = __float2bfloat16(acc[i][j] + bias[n]);
      }
    }
  }
}

// N must be 512: cols 0-255 -> Ck (bf16), cols 256-511 -> Cv (f32)
__global__ __launch_bounds__(256, 2)
void gemm_bt_kv(const float* __restrict__ A, const float* __restrict__ W,
                const float* __restrict__ bias, __hip_bfloat16* __restrict__ Ck,
                float* __restrict__ Cv, int M, int K) {
  const int N = 512;
  GEMM_BODY
  #pragma unroll
  for (int i = 0; i < 4; ++i) {
    const int m = m0 + ty * 4 + i;
    if (m < M) {
      #pragma unroll
      for (int j = 0; j < 4; ++j) {
        const int n = n0 + tx * 4 + j;
        const float val = acc[i][j] + bias[n];
        if (n < 256) Ck[(size_t)m * 256 + n] = __float2bfloat16(val);
        else         Cv[(size_t)m * 256 + (n - 256)] = val;
      }
    }
  }
}

// ---------------------------------------------------------------------------
// Fused cpb-MLP + flash attention, MFMA QK.
// Block = (b, 16 q-rows), 256 threads = 4 waves; wave w owns heads 2w,2w+1.
// Chunk = 32 keys. Per chunk:
//   [all]    cooperative cpb MLP (2 pairs/thread, LDS weights, fenced)
//   barrier
//   [wave]   QK via mfma_f32_16x16x32_bf16 (2 heads x 2 key-subtiles),
//            + cpb + mask + in-register online softmax (D-frag layout),
//            P/alpha -> same-wave LDS (no barrier needed)
//   [thread] PV on VALU: thread = (head, dim); broadcast float4 ps reads
//   barrier
// ---------------------------------------------------------------------------
#define SCALE 0.17677669529663687f

__global__ __launch_bounds__(256, 1)
void attn_fused(const __hip_bfloat16* __restrict__ qb,  // [4*900,256] bf16
                const __hip_bfloat16* __restrict__ kb,  // [4*1024,256] bf16
                const float* __restrict__ vb,           // [4*1024,256] f32
                const float* __restrict__ dist,         // [4,900,1024,2]
                const unsigned char* __restrict__ mask, // [4,1024]
                const float* __restrict__ Wc1, const float* __restrict__ bc1,
                const float* __restrict__ Wc2, const float* __restrict__ bc2,
                float* __restrict__ obuf) {             // [4*900,256] f32
  __shared__ float cpb_lds[8][16][36];   // 18.4 KB  [h][q][k]
  __shared__ float ps[8][16][36];        // 18.4 KB  [h][q][k]
  __shared__ float astate[8][16];
  __shared__ float lst[8][16];
  __shared__ float4 wpack[64][3];

  const int t    = threadIdx.x;
  const int b    = blockIdx.x / 57;
  const int q0   = (blockIdx.x % 57) * 16;
  const int lane = t & 63;
  const int w    = t >> 6;

  // --- MLP weights -> LDS ---
  if (t < 64) {
    wpack[t][0] = make_float4(Wc1[2 * t], Wc1[2 * t + 1], bc1[t], 0.f);
    wpack[t][1] = make_float4(Wc2[0 * 64 + t], Wc2[1 * 64 + t],
                              Wc2[2 * 64 + t], Wc2[3 * 64 + t]);
    wpack[t][2] = make_float4(Wc2[4 * 64 + t], Wc2[5 * 64 + t],
                              Wc2[6 * 64 + t], Wc2[7 * 64 + t]);
  }
  float b2r[8];
  #pragma unroll
  for (int h = 0; h < 8; ++h) b2r[8 - 1 - h] = bc2[8 - 1 - h];

  // --- Q A-fragments (held in 8 VGPRs for the whole kernel) ---
  const int fr = lane & 15;   // A row / B col / D col
  const int fk = lane >> 4;   // k-group
  int qrow = q0 + fr; if (qrow > 899) qrow = 899;
  short8 aq[2];
  #pragma unroll
  for (int h2 = 0; h2 < 2; ++h2)
    aq[h2] = *(const short8*)&qb[(size_t)(b * 900 + qrow) * 256 +
                                 (2 * w + h2) * 32 + fk * 8];

  // --- softmax state (registers, replicated across 16 lanes of a row) ---
  float mreg[2][4], lreg[2][4];
  #pragma unroll
  for (int h2 = 0; h2 < 2; ++h2)
    #pragma unroll
    for (int r = 0; r < 4; ++r) { mreg[h2][r] = -1e30f; lreg[h2][r] = 0.f; }

  // --- PV role ---
  const int ph = t >> 5, pd = t & 31;
  float O[16];
  #pragma unroll
  for (int q = 0; q < 16; ++q) O[q] = 0.f;

  // --- MLP pair assignment: thread t owns pairs (mq, mk) and (mq, mk+1) ---
  const int mq = t >> 4;
  const int mk = (2 * t) & 31;
  int mqrow = q0 + mq; if (mqrow > 899) mqrow = 899;
  const size_t drow = ((size_t)(b * 900 + mqrow)) * 2048;

  __syncthreads();

  for (int c = 0; c < 32; ++c) {
    const int k0 = c * 32;

    // ---- cooperative cpb MLP: 2 pairs/thread, shared weight loads ----
    const float4 d4 = *(const float4*)&dist[drow + (size_t)(k0 + mk) * 2];
    float cp0[8], cp1[8];
    #pragma unroll
    for (int h = 0; h < 8; ++h) { cp0[h] = 0.f; cp1[h] = 0.f; }
    for (int jo = 0; jo < 16; ++jo) {
      #pragma unroll
      for (int ji = 0; ji < 4; ++ji) {
        const int jl = jo * 4 + ji;
        const float4 w1 = wpack[jl][0];
        const float h0 = fmaxf(fmaf(w1.x, d4.x, fmaf(w1.y, d4.y, w1.z)), 0.f);
        const float h1 = fmaxf(fmaf(w1.x, d4.z, fmaf(w1.y, d4.w, w1.z)), 0.f);
        const float4 wa = wpack[jl][1];
        const float4 wb = wpack[jl][2];
        cp0[0] = fmaf(wa.x, h0, cp0[0]); cp1[0] = fmaf(wa.x, h1, cp1[0]);
        cp0[1] = fmaf(wa.y, h0, cp0[1]); cp1[1] = fmaf(wa.y, h1, cp1[1]);
        cp0[2] = fmaf(wa.z, h0, cp0[2]); cp1[2] = fmaf(wa.z, h1, cp1[2]);
        cp0[3] = fmaf(wa.w, h0, cp0[3]); cp1[3] = fmaf(wa.w, h1, cp1[3]);
        cp0[4] = fmaf(wb.x, h0, cp0[4]); cp1[4] = fmaf(wb.x, h1, cp1[4]);
        cp0[5] = fmaf(wb.y, h0, cp0[5]); cp1[5] = fmaf(wb.y, h1, cp1[5]);
        cp0[6] = fmaf(wb.z, h0, cp0[6]); cp1[6] = fmaf(wb.z, h1, cp1[6]);
        cp0[7] = fmaf(wb.w, h0, cp0[7]); cp1[7] = fmaf(wb.w, h1, cp1[7]);
      }
      __builtin_amdgcn_sched_barrier(0);
    }
    #pragma unroll
    for (int h = 0; h < 8; ++h) {
      cpb_lds[h][mq][mk]     = cp0[h] + b2r[h];
      cpb_lds[h][mq][mk + 1] = cp1[h] + b2r[h];
    }
    __syncthreads();   // cpb ready for all waves

    // ---- QK: 4 MFMAs per wave (2 heads x 2 key-subtiles) ----
    f32x4 sc[2][2];
    #pragma unroll
    for (int h2 = 0; h2 < 2; ++h2)
      #pragma unroll
      for (int sub = 0; sub < 2; ++sub) {
        const short8 kf = *(const short8*)
            &kb[(size_t)(b * 1024 + k0 + sub * 16 + fr) * 256 +
                (2 * w + h2) * 32 + fk * 8];
        f32x4 z = {0.f, 0.f, 0.f, 0.f};
        sc[h2][sub] =
            __builtin_amdgcn_mfma_f32_16x16x32_bf16(aq[h2], kf, z, 0, 0, 0);
      }
    const bool msk0 = mask[b * 1024 + k0 + fr] != 0;
    const bool msk1 = mask[b * 1024 + k0 + 16 + fr] != 0;

    // ---- online softmax per head, D-frag layout ----
    #pragma unroll
    for (int h2 = 0; h2 < 2; ++h2) {
      const int h = 2 * w + h2;
      float s0[4], s1[4], mx[4];
      #pragma unroll
      for (int r = 0; r < 4; ++r) {
        const int q = fk * 4 + r;
        s0[r] = msk0 ? -1e30f
                     : fmaf(sc[h2][0][r], SCALE, cpb_lds[h][q][fr]);
        s1[r] = msk1 ? -1e30f
                     : fmaf(sc[h2][1][r], SCALE, cpb_lds[h][q][16 + fr]);
        mx[r] = fmaxf(s0[r], s1[r]);
      }
      #pragma unroll
      for (int r = 0; r < 4; ++r) {
        mx[r] = fmaxf(mx[r], __shfl_xor(mx[r], 1));
        mx[r] = fmaxf(mx[r], __shfl_xor(mx[r], 2));
        mx[r] = fmaxf(mx[r], __shfl_xor(mx[r], 4));
        mx[r] = fmaxf(mx[r], __shfl_xor(mx[r], 8));
      }
      #pragma unroll
      for (int r = 0; r < 4; ++r) {
        const int q = fk * 4 + r;
        const float mnew = fmaxf(mreg[h2][r], mx[r]);
        const float al   = __expf(mreg[h2][r] - mnew);
        const float p0   = __expf(s0[r] - mnew);
        const float p1   = __expf(s1[r] - mnew);
        ps[h][q][fr]      = p0;
        ps[h][q][16 + fr] = p1;
        float pr = p0 + p1;
        pr += __shfl_xor(pr, 1);
        pr += __shfl_xor(pr, 2);
        pr += __shfl_xor(pr, 4);
        pr += __shfl_xor(pr, 8);
        lreg[h2][r] = lreg[h2][r] * al + pr;
        mreg[h2][r] = mnew;
        if (fr == 0) astate[h][q] = al;
      }
    }
    // ps/astate are same-wave for the PV role below: no barrier needed.

    // ---- PV: thread = (head ph, dim pd) ----
    #pragma unroll
    for (int q = 0; q < 16; ++q) {
      O[q] *= astate[ph][q];
      if ((q & 7) == 7) __builtin_amdgcn_sched_barrier(0);
    }
    const float* vp = &vb[(size_t)(b * 1024 + k0) * 256 + ph * 32 + pd];
    for (int g = 0; g < 8; ++g) {
      const float v0 = vp[(size_t)(g * 4 + 0) * 256];
      const float v1 = vp[(size_t)(g * 4 + 1) * 256];
      const float v2 = vp[(size_t)(g * 4 + 2) * 256];
      const float v3 = vp[(size_t)(g * 4 + 3) * 256];
      #pragma unroll
      for (int q = 0; q < 16; ++q) {
        const float4 p4 = *(const float4*)&ps[ph][q][g * 4];
        float o = O[q];
        o = fmaf(p4.x, v0, o); o = fmaf(p4.y, v1, o);
        o = fmaf(p4.z, v2, o); o = fmaf(p4.w, v3, o);
        O[q] = o;
        if ((q & 7) == 7) __builtin_amdgcn_sched_barrier(0);
      }
    }
    __syncthreads();   // protect cpb_lds for next chunk's MLP writes
  }

  // ---- epilogue: divide by l, store ----
  #pragma unroll
  for (int h2 = 0; h2 < 2; ++h2)
    #pragma unroll
    for (int r = 0; r < 4; ++r)
      if (fr == 0) lst[2 * w + h2][fk * 4 + r] = lreg[h2][r];
  // same-wave LDS: lgkmcnt orders write->read
  #pragma unroll
  for (int q = 0; q < 16; ++q) {
    const int qq = q0 + q;
    if (qq < 900)
      obuf[(size_t)(b * 900 + qq) * 256 + ph * 32 + pd] = O[q] / lst[ph][q];
  }
}

// ---------------------------------------------------------------------------
extern "C" void kernel_launch(void* const* d_in, const int* in_sizes, int n_in,
                              void* d_out, int out_size, void* d_ws, size_t ws_size,
                              hipStream_t stream) {
  const float* nodes  = (const float*)d_in[0];
  const float* images = (const float*)d_in[1];
  const unsigned char* mask = (const unsigned char*)d_in[2];
  const float* dist   = (const float*)d_in[3];
  const float* Wq     = (const float*)d_in[4];
  const float* bq     = (const float*)d_in[5];
  const float* Wkv    = (const float*)d_in[6];
  const float* bkv    = (const float*)d_in[7];
  const float* Wc1    = (const float*)d_in[8];
  const float* bc1    = (const float*)d_in[9];
  const float* Wc2    = (const float*)d_in[10];
  const float* bc2    = (const float*)d_in[11];
  const float* Wo     = (const float*)d_in[12];
  const float* bo     = (const float*)d_in[13];
  float* out = (float*)d_out;

  float* vbuf = (float*)d_ws;                         // 4096*256 f32
  float* obuf = vbuf + 4096 * 256;                    // 3600*256 f32
  __hip_bfloat16* qb = (__hip_bfloat16*)(obuf + 3600 * 256);  // 3600*256 bf16
  __hip_bfloat16* kb = qb + 3600 * 256;               // 4096*256 bf16

  gemm_bt_bf16<<<dim3(4, 57), 256, 0, stream>>>(nodes, Wq, bq, qb, 3600, 256, 256);
  gemm_bt_kv<<<dim3(8, 64), 256, 0, stream>>>(images, Wkv, bkv, kb, vbuf, 4096, 256);
  attn_fused<<<dim3(228), 256, 0, stream>>>(qb, kb, vbuf, dist, mask,
                                            Wc1, bc1, Wc2, bc2, obuf);
  gemm_bt_f32<<<dim3(4, 57), 256, 0, stream>>>(obuf, Wo, bo, out, 3600, 256, 256);
}

// Round 5
// 150.984 us; speedup vs baseline: 62.9493x; 2.6212x over previous
//
#include <hip/hip_runtime.h>
#include <hip/hip_bf16.h>

typedef float f32x4 __attribute__((ext_vector_type(4)));
typedef short short8 __attribute__((ext_vector_type(8)));

static __device__ __forceinline__ short f2bf(float x) {
  union { __hip_bfloat16 b; short s; } u;
  u.b = __float2bfloat16(x);
  return u.s;
}

// ---------------------------------------------------------------------------
// GEMM C[M,N] = A[M,K] @ W[N,K]^T + bias[N], 64x64 tile, 4x4 microtile.
// ---------------------------------------------------------------------------
#define GEMM_BODY                                                            \
  __shared__ float As[16][68];                                               \
  __shared__ float Ws[16][68];                                               \
  const int t  = threadIdx.x;                                                \
  const int tx = t & 15, ty = t >> 4;                                        \
  const int m0 = blockIdx.y * 64, n0 = blockIdx.x * 64;                      \
  const int lr = t >> 2;                                                     \
  const int lk = (t & 3) * 4;                                                \
  float acc[4][4];                                                           \
  _Pragma("unroll") for (int i = 0; i < 4; ++i)                              \
      _Pragma("unroll") for (int j = 0; j < 4; ++j) acc[i][j] = 0.f;         \
  for (int k0 = 0; k0 < K; k0 += 16) {                                       \
    int am = m0 + lr; if (am > M - 1) am = M - 1;                            \
    const float4 a4 = *(const float4*)&A[(size_t)am * K + k0 + lk];          \
    const float4 w4 = *(const float4*)&W[(size_t)(n0 + lr) * K + k0 + lk];   \
    __syncthreads();                                                         \
    As[lk + 0][lr] = a4.x; As[lk + 1][lr] = a4.y;                            \
    As[lk + 2][lr] = a4.z; As[lk + 3][lr] = a4.w;                            \
    Ws[lk + 0][lr] = w4.x; Ws[lk + 1][lr] = w4.y;                            \
    Ws[lk + 2][lr] = w4.z; Ws[lk + 3][lr] = w4.w;                            \
    __syncthreads();                                                         \
    _Pragma("unroll") for (int kk = 0; kk < 16; ++kk) {                      \
      const float4 av = *(const float4*)&As[kk][ty * 4];                     \
      const float4 wv = *(const float4*)&Ws[kk][tx * 4];                     \
      const float ar[4] = {av.x, av.y, av.z, av.w};                          \
      const float wr[4] = {wv.x, wv.y, wv.z, wv.w};                          \
      _Pragma("unroll") for (int i = 0; i < 4; ++i)                          \
          _Pragma("unroll") for (int j = 0; j < 4; ++j)                      \
              acc[i][j] = fmaf(ar[i], wr[j], acc[i][j]);                     \
    }                                                                        \
  }

__global__ __launch_bounds__(256, 2)
void gemm_bt_f32(const float* __restrict__ A, const float* __restrict__ W,
                 const float* __restrict__ bias, float* __restrict__ C,
                 int M, int N, int K) {
  GEMM_BODY
  #pragma unroll
  for (int i = 0; i < 4; ++i) {
    const int m = m0 + ty * 4 + i;
    if (m < M) {
      #pragma unroll
      for (int j = 0; j < 4; ++j) {
        const int n = n0 + tx * 4 + j;
        C[(size_t)m * N + n] = acc[i][j] + bias[n];
      }
    }
  }
}

__global__ __launch_bounds__(256, 2)
void gemm_bt_bf16(const float* __restrict__ A, const float* __restrict__ W,
                  const float* __restrict__ bias, __hip_bfloat16* __restrict__ C,
                  int M, int N, int K) {
  GEMM_BODY
  #pragma unroll
  for (int i = 0; i < 4; ++i) {
    const int m = m0 + ty * 4 + i;
    if (m < M) {
      #pragma unroll
      for (int j = 0; j < 4; ++j) {
        const int n = n0 + tx * 4 + j;
        C[(size_t)m * N + n] = __float2bfloat16(acc[i][j] + bias[n]);
      }
    }
  }
}

// N=512: cols 0-255 -> K bf16 [m][256]; cols 256-511 -> V^T bf16 [b][d][1024]
__global__ __launch_bounds__(256, 2)
void gemm_bt_kv(const float* __restrict__ A, const float* __restrict__ W,
                const float* __restrict__ bias, __hip_bfloat16* __restrict__ Ck,
                __hip_bfloat16* __restrict__ vT, int M, int K) {
  const int N = 512;
  GEMM_BODY
  #pragma unroll
  for (int i = 0; i < 4; ++i) {
    const int m = m0 + ty * 4 + i;
    if (m < M) {
      #pragma unroll
      for (int j = 0; j < 4; ++j) {
        const int n = n0 + tx * 4 + j;
        const float val = acc[i][j] + bias[n];
        if (n < 256) {
          Ck[(size_t)m * 256 + n] = __float2bfloat16(val);
        } else {
          vT[((size_t)(m >> 10) * 256 + (n - 256)) * 1024 + (m & 1023)] =
              __float2bfloat16(val);
        }
      }
    }
  }
}

// ---------------------------------------------------------------------------
// Fused cpb-MLP + flash attention, all-MFMA matmuls.
// Block = (b, 16 q-rows), 512 threads = 8 waves; wave w owns head w.
// Per 32-key chunk:
//   MLP: layer1 on VALU with per-lane VGPR weights (lane fk-group owns its
//        16 hidden units); layer2 = 2 MFMA per 16-pair tile, W2 as a
//        register-resident B-frag (loaded once). 4 tiles/wave = 64 pairs
//        (q rows 2w, 2w+1). D-frag -> cpb_lds[h][q][k].  [barrier]
//   QK:  2 MFMA (2 key-subtiles); softmax in D-frag layout, m/l/alpha
//        lane-local; P -> per-wave bf16 LDS tile. [lgkmcnt, same wave]
//   PV:  P A-frag = 1 ds_read_b128; V B-frags = contiguous short8 from vT;
//        2 MFMA accumulate into O D-frag (rescale lane-local). [barrier]
// ---------------------------------------------------------------------------
#define SCALE 0.17677669529663687f

__global__ __launch_bounds__(512, 2)
void attn_fused(const __hip_bfloat16* __restrict__ qb,  // [4*900,256]
                const __hip_bfloat16* __restrict__ kb,  // [4*1024,256]
                const __hip_bfloat16* __restrict__ vT,  // [4,256,1024]
                const float* __restrict__ dist,         // [4,900,1024,2]
                const unsigned char* __restrict__ mask, // [4,1024]
                const float* __restrict__ Wc1, const float* __restrict__ bc1,
                const float* __restrict__ Wc2, const float* __restrict__ bc2,
                float* __restrict__ obuf) {             // [4*900,256] f32
  __shared__ float cpb_s[8 * 552];     // [h][q*34 + k], padded
  __shared__ short ps_s[8][640];       // per-wave P bf16 [q][40 pad]

  const int t    = threadIdx.x;
  const int b    = blockIdx.x / 57;
  const int q0   = (blockIdx.x % 57) * 16;
  const int w    = t >> 6;             // wave = head
  const int lane = t & 63;
  const int fr   = lane & 15;
  const int fk   = lane >> 4;

  // --- per-lane MLP weights (layer 1: 16 hidden units j = m*32+fk*8+jj) ---
  float w1x[2][8], w1y[2][8], w1b[2][8];
  #pragma unroll
  for (int m = 0; m < 2; ++m)
    #pragma unroll
    for (int jj = 0; jj < 8; ++jj) {
      const int j = m * 32 + fk * 8 + jj;
      w1x[m][jj] = Wc1[2 * j];
      w1y[m][jj] = Wc1[2 * j + 1];
      w1b[m][jj] = bc1[j];
    }
  // --- W2 as register B-frag: col = fr (head, <8), k = m*32+fk*8+jj ---
  short8 w2f[2];
  #pragma unroll
  for (int m = 0; m < 2; ++m)
    #pragma unroll
    for (int jj = 0; jj < 8; ++jj) {
      const float v = (fr < 8) ? Wc2[fr * 64 + m * 32 + fk * 8 + jj] : 0.f;
      w2f[m][jj] = f2bf(v);
    }
  const float b2add = (fr < 8) ? bc2[fr] : 0.f;

  // --- Q A-frag (persistent) ---
  int qrow = q0 + fr; if (qrow > 899) qrow = 899;
  const short8 aq = *(const short8*)&qb[(size_t)(b * 900 + qrow) * 256 +
                                        w * 32 + fk * 8];

  // --- dist pointers, one per MLP tile; prefetch chunk 0 ---
  const float* dptr[4];
  float2 d2cur[4];
  #pragma unroll
  for (int t4 = 0; t4 < 4; ++t4) {
    int qg = q0 + 2 * w + (t4 >> 1); if (qg > 899) qg = 899;
    dptr[t4] = dist + ((size_t)(b * 900 + qg) * 1024 + (t4 & 1) * 16 + fr) * 2;
    d2cur[t4] = *(const float2*)dptr[t4];
  }

  f32x4 of[2];
  of[0] = (f32x4){0.f, 0.f, 0.f, 0.f};
  of[1] = (f32x4){0.f, 0.f, 0.f, 0.f};
  float mreg[4], lreg[4], alpha[4];
  #pragma unroll
  for (int r = 0; r < 4; ++r) { mreg[r] = -1e30f; lreg[r] = 0.f; }

  __syncthreads();

  for (int c = 0; c < 32; ++c) {
    const int k0 = c * 32;
    const int cn = (c < 31) ? c + 1 : c;

    // ---- prefetch next chunk's dist; issue this chunk's K/V/mask ----
    float2 d2n[4];
    #pragma unroll
    for (int t4 = 0; t4 < 4; ++t4)
      d2n[t4] = *(const float2*)(dptr[t4] + (size_t)cn * 64);
    const short8 kf0 = *(const short8*)
        &kb[(size_t)(b * 1024 + k0 + fr) * 256 + w * 32 + fk * 8];
    const short8 kf1 = *(const short8*)
        &kb[(size_t)(b * 1024 + k0 + 16 + fr) * 256 + w * 32 + fk * 8];
    const short8 bv0 = *(const short8*)
        &vT[(size_t)(b * 256 + w * 32 + fr) * 1024 + k0 + fk * 8];
    const short8 bv1 = *(const short8*)
        &vT[(size_t)(b * 256 + w * 32 + 16 + fr) * 1024 + k0 + fk * 8];
    const bool mk0 = mask[b * 1024 + k0 + fr] != 0;
    const bool mk1 = mask[b * 1024 + k0 + 16 + fr] != 0;

    // ---- cpb MLP: 4 tiles x (layer1 VALU + 2 MFMA layer2) ----
    #pragma unroll
    for (int t4 = 0; t4 < 4; ++t4) {
      const float dx = d2cur[t4].x, dy = d2cur[t4].y;
      short8 a0, a1;
      #pragma unroll
      for (int jj = 0; jj < 8; ++jj) {
        const float h0 =
            fmaxf(fmaf(w1x[0][jj], dx, fmaf(w1y[0][jj], dy, w1b[0][jj])), 0.f);
        const float h1 =
            fmaxf(fmaf(w1x[1][jj], dx, fmaf(w1y[1][jj], dy, w1b[1][jj])), 0.f);
        a0[jj] = f2bf(h0);
        a1[jj] = f2bf(h1);
      }
      f32x4 z = {0.f, 0.f, 0.f, 0.f};
      f32x4 dcp = __builtin_amdgcn_mfma_f32_16x16x32_bf16(a1, w2f[1], z, 0, 0, 0);
      dcp = __builtin_amdgcn_mfma_f32_16x16x32_bf16(a0, w2f[0], dcp, 0, 0, 0);
      const int qloc = 2 * w + (t4 >> 1);
      const int kbase = (t4 & 1) * 16;
      if (fr < 8) {
        #pragma unroll
        for (int rr = 0; rr < 4; ++rr)
          cpb_s[fr * 552 + qloc * 34 + kbase + fk * 4 + rr] = dcp[rr] + b2add;
      }
      __builtin_amdgcn_sched_barrier(0);
    }
    __syncthreads();   // cpb ready for all waves

    // ---- QK: 2 MFMA ----
    f32x4 z = {0.f, 0.f, 0.f, 0.f};
    const f32x4 sc0 = __builtin_amdgcn_mfma_f32_16x16x32_bf16(aq, kf0, z, 0, 0, 0);
    const f32x4 sc1 = __builtin_amdgcn_mfma_f32_16x16x32_bf16(aq, kf1, z, 0, 0, 0);

    // ---- online softmax (D-frag layout; m/l/alpha lane-local) ----
    #pragma unroll
    for (int r = 0; r < 4; ++r) {
      const int q = fk * 4 + r;
      const float cv0 = cpb_s[w * 552 + q * 34 + fr];
      const float cv1 = cpb_s[w * 552 + q * 34 + 16 + fr];
      const float s0 = mk0 ? -1e30f : fmaf(sc0[r], SCALE, cv0);
      const float s1 = mk1 ? -1e30f : fmaf(sc1[r], SCALE, cv1);
      float mx = fmaxf(s0, s1);
      mx = fmaxf(mx, __shfl_xor(mx, 1));
      mx = fmaxf(mx, __shfl_xor(mx, 2));
      mx = fmaxf(mx, __shfl_xor(mx, 4));
      mx = fmaxf(mx, __shfl_xor(mx, 8));
      const float mnew = fmaxf(mreg[r], mx);
      alpha[r] = __expf(mreg[r] - mnew);
      const float p0 = __expf(s0 - mnew);
      const float p1 = __expf(s1 - mnew);
      ps_s[w][q * 40 + fr]      = f2bf(p0);
      ps_s[w][q * 40 + 16 + fr] = f2bf(p1);
      float pr = p0 + p1;
      pr += __shfl_xor(pr, 1);
      pr += __shfl_xor(pr, 2);
      pr += __shfl_xor(pr, 4);
      pr += __shfl_xor(pr, 8);
      lreg[r] = lreg[r] * alpha[r] + pr;
      mreg[r] = mnew;
    }

    // same-wave LDS write -> read: drain lgkm, pin order
    asm volatile("s_waitcnt lgkmcnt(0)" ::: "memory");
    __builtin_amdgcn_sched_barrier(0);

    // ---- PV: P A-frag (1 ds_read_b128), V B-frags, 2 MFMA ----
    const short8 ap = *(const short8*)&ps_s[w][fr * 40 + fk * 8];
    #pragma unroll
    for (int s = 0; s < 2; ++s)
      #pragma unroll
      for (int r = 0; r < 4; ++r) of[s][r] *= alpha[r];
    of[0] = __builtin_amdgcn_mfma_f32_16x16x32_bf16(ap, bv0, of[0], 0, 0, 0);
    of[1] = __builtin_amdgcn_mfma_f32_16x16x32_bf16(ap, bv1, of[1], 0, 0, 0);

    #pragma unroll
    for (int t4 = 0; t4 < 4; ++t4) d2cur[t4] = d2n[t4];
    __syncthreads();   // protect cpb_s for next chunk's MLP writes
  }

  // ---- epilogue: O / l, D-frag coalesced stores ----
  #pragma unroll
  for (int s = 0; s < 2; ++s)
    #pragma unroll
    for (int r = 0; r < 4; ++r) {
      const int qg = q0 + fk * 4 + r;
      if (qg < 900)
        obuf[(size_t)(b * 900 + qg) * 256 + w * 32 + s * 16 + fr] =
            of[s][r] / lreg[r];
    }
}

// ---------------------------------------------------------------------------
extern "C" void kernel_launch(void* const* d_in, const int* in_sizes, int n_in,
                              void* d_out, int out_size, void* d_ws, size_t ws_size,
                              hipStream_t stream) {
  const float* nodes  = (const float*)d_in[0];
  const float* images = (const float*)d_in[1];
  const unsigned char* mask = (const unsigned char*)d_in[2];
  const float* dist   = (const float*)d_in[3];
  const float* Wq     = (const float*)d_in[4];
  const float* bq     = (const float*)d_in[5];
  const float* Wkv    = (const float*)d_in[6];
  const float* bkv    = (const float*)d_in[7];
  const float* Wc1    = (const float*)d_in[8];
  const float* bc1    = (const float*)d_in[9];
  const float* Wc2    = (const float*)d_in[10];
  const float* bc2    = (const float*)d_in[11];
  const float* Wo     = (const float*)d_in[12];
  const float* bo     = (const float*)d_in[13];
  float* out = (float*)d_out;

  float* obuf = (float*)d_ws;                             // 3600*256 f32
  __hip_bfloat16* qb = (__hip_bfloat16*)(obuf + 3600 * 256);  // 3600*256
  __hip_bfloat16* kb = qb + 3600 * 256;                   // 4096*256
  __hip_bfloat16* vT = kb + 4096 * 256;                   // 4*256*1024

  gemm_bt_bf16<<<dim3(4, 57), 256, 0, stream>>>(nodes, Wq, bq, qb, 3600, 256, 256);
  gemm_bt_kv<<<dim3(8, 64), 256, 0, stream>>>(images, Wkv, bkv, kb, vT, 4096, 256);
  attn_fused<<<dim3(228), 512, 0, stream>>>(qb, kb, vT, dist, mask,
                                            Wc1, bc1, Wc2, bc2, obuf);
  gemm_bt_f32<<<dim3(4, 57), 256, 0, stream>>>(obuf, Wo, bo, out, 3600, 256, 256);
}